// Round 2
// baseline (268.244 us; speedup 1.0000x reference)
//
#include <hip/hip_runtime.h>

// Problem constants: B=16, S=2048, D=1024, P=8192, R=16, NL=64, span<=31
#define S_LEN      2048
#define D_DIM      1024
#define R_DIM      16
#define OUT_STRIDE 2064          // 2*D + R
#define NBUCK      8192          // (B*S)>>2 coarse sort buckets (32 KB LDS hist)
#define BPT        8             // buckets per thread in the scan (NBUCK/1024)
#define GROUP      4             // sorted jobs per gather group
#define NR         4             // rows per LDS chunk (chunk = NR*4KB = 16 KB)

// ---------------------------------------------------------------------------
// Fused counting sort of the 2P span-jobs by coarse start bucket
// ((b*S + s) >> 2). One workgroup, everything in LDS: zero + histogram +
// scan + scatter in a single dispatch.
__global__ __launch_bounds__(1024) void sort_jobs(
    const int* __restrict__ bidx, const int* __restrict__ e1s,
    const int* __restrict__ e2s, int* __restrict__ sorted, int njobs)
{
    __shared__ int hist[NBUCK];   // 32 KB
    __shared__ int part[1024];    // 4 KB
    const int t = threadIdx.x;

#pragma unroll
    for (int i = 0; i < BPT; ++i) hist[t * BPT + i] = 0;
    __syncthreads();

    for (int j = t; j < njobs; j += 1024) {
        const int p = j >> 1;
        const int s = (j & 1) ? e2s[p] : e1s[p];
        atomicAdd(&hist[(bidx[p] * S_LEN + s) >> 2], 1);
    }
    __syncthreads();

    int v[BPT];
    int sum = 0;
#pragma unroll
    for (int i = 0; i < BPT; ++i) { v[i] = hist[t * BPT + i]; sum += v[i]; }
    part[t] = sum;
    __syncthreads();
    for (int off = 1; off < 1024; off <<= 1) {
        int x = (t >= off) ? part[t - off] : 0;
        __syncthreads();
        part[t] += x;
        __syncthreads();
    }
    int run = (t == 0) ? 0 : part[t - 1];
#pragma unroll
    for (int i = 0; i < BPT; ++i) { int c = v[i]; hist[t * BPT + i] = run; run += c; }
    __syncthreads();

    for (int j = t; j < njobs; j += 1024) {
        const int p = j >> 1;
        const int s = (j & 1) ? e2s[p] : e1s[p];
        const int pos = atomicAdd(&hist[(bidx[p] * S_LEN + s) >> 2], 1);
        sorted[pos] = j;
    }
}

// ---------------------------------------------------------------------------
// Async global->LDS 16B DMA: wave-uniform LDS dest + lane*16 implicit,
// per-lane global src. The compiler cannot register-allocate this pipeline
// away (the in-flight data lives in the DMA queue, not VGPRs) -- which is
// exactly what killed v3/v4's register prefetch (VGPR squeezed to 48/32,
// waits collapsed to vmcnt(0)-before-FMA, latency fully exposed).
__device__ __forceinline__ void load16_lds(const float* g, float* l) {
    __builtin_amdgcn_global_load_lds(
        (const __attribute__((address_space(1))) void*)g,
        (__attribute__((address_space(3))) void*)l, 16, 0, 0);
}

// ---------------------------------------------------------------------------
// Grouped gather v5: LDS double-buffered staging. One block = one group of
// 4 sorted jobs x full 1024 cols; 256 threads (4 waves). Per chunk of NR=4
// rows: wave w DMAs row w of the NEXT chunk (4x global_load_lds of 1KB)
// while all threads accumulate the CURRENT chunk from LDS (ds_read_b128 +
// branch-free weighted FMA). __syncthreads() per chunk provides the
// vmcnt(0) drain that hands the staged chunk over. Rows clamped to the
// window's last row; out-of-span rows get weight 0.
__global__ __launch_bounds__(256) void gather_lds(
    const float* __restrict__ tok,     // [B*S, D] fp32
    const int*   __restrict__ sorted,  // [2P] sorted job ids
    const int*   __restrict__ bidx,
    const int*   __restrict__ e1s, const int* __restrict__ e1e,
    const int*   __restrict__ e2s, const int* __restrict__ e2e,
    const int*   __restrict__ ridx,
    const float* __restrict__ rtab,    // [NL, R]
    float*       __restrict__ out)     // [P, 2D+R]
{
    __shared__ float buf[2][NR * D_DIM];   // 2 x 16 KB

    const int blk = blockIdx.x;
    // XCD swizzle: contiguous group ranges per XCD -> sliding row window in L2
    const int g  = (blk & 7) * (gridDim.x >> 3) + (blk >> 3);
    const int t  = threadIdx.x;        // 0..255, 4 cols each
    const int wv = t >> 6;             // wave id 0..3
    const int ln = t & 63;

    int   jp[GROUP], jh[GROUP], js[GROUP], je[GROUP];
    float jw[GROUP];
    int mins = 0x7fffffff, maxe = 0;
#pragma unroll
    for (int i = 0; i < GROUP; ++i) {
        const int id = __builtin_amdgcn_readfirstlane(sorted[g * GROUP + i]);
        const int p  = id >> 1;
        const int h  = id & 1;
        const int b  = __builtin_amdgcn_readfirstlane(bidx[p]);
        const int s  = __builtin_amdgcn_readfirstlane(h ? e2s[p] : e1s[p]);
        const int e  = __builtin_amdgcn_readfirstlane(h ? e2e[p] : e1e[p]);
        jp[i] = p; jh[i] = h;
        js[i] = b * S_LEN + s;
        je[i] = b * S_LEN + e;
        jw[i] = 1.0f / (float)(e - s);
        mins  = min(mins, js[i]);
        maxe  = max(maxe, je[i]);
    }

    const int nrows = maxe - mins;            // >= 1
    const int rmaxg = maxe - 1;               // last valid global row
    const int niter = (nrows + NR - 1) / NR;

    // stage chunk c into buffer bi: wave wv stages chunk-row wv (clamped)
    auto stage = [&](int bi, int c) {
        const int grow = min(mins + c * NR + wv, rmaxg);
        const float* src = tok + (size_t)grow * D_DIM + ln * 4;
        float* dst = &buf[bi][wv * D_DIM];
#pragma unroll
        for (int q = 0; q < 4; ++q)
            load16_lds(src + q * 256, dst + q * 256);
    };

    stage(0, 0);

    float4 acc[GROUP];
#pragma unroll
    for (int i = 0; i < GROUP; ++i) acc[i] = make_float4(0.f, 0.f, 0.f, 0.f);

    __syncthreads();                          // chunk 0 landed

    for (int c = 0; c < niter; ++c) {
        if (c + 1 < niter) stage((c + 1) & 1, c + 1);   // overlap next DMA

        const int cb  = c & 1;
        const int gr0 = mins + c * NR;
#pragma unroll
        for (int r = 0; r < NR; ++r) {
            const float4 v = *reinterpret_cast<const float4*>(
                &buf[cb][r * D_DIM + t * 4]);
            const int gr = gr0 + r;
#pragma unroll
            for (int i = 0; i < GROUP; ++i) {  // wave-uniform scalar weights
                const float w = (gr >= js[i] && gr < je[i]) ? jw[i] : 0.f;
                acc[i].x += v.x * w;
                acc[i].y += v.y * w;
                acc[i].z += v.z * w;
                acc[i].w += v.w * w;
            }
        }
        __syncthreads();   // drains next-chunk DMA; releases buf[cb] for reuse
    }

#pragma unroll
    for (int i = 0; i < GROUP; ++i) {
        float* dst = out + (size_t)jp[i] * OUT_STRIDE + jh[i] * D_DIM + t * 4;
        *reinterpret_cast<float4*>(dst) = acc[i];
        if (jh[i] == 0 && t < 4) {             // rel row once per pair
            const float4 rv = *reinterpret_cast<const float4*>(
                rtab + ridx[jp[i]] * R_DIM + t * 4);
            *reinterpret_cast<float4*>(
                out + (size_t)jp[i] * OUT_STRIDE + 2 * D_DIM + t * 4) = rv;
        }
    }
}

// ---------------------------------------------------------------------------
extern "C" void kernel_launch(void* const* d_in, const int* in_sizes, int n_in,
                              void* d_out, int out_size, void* d_ws, size_t ws_size,
                              hipStream_t stream) {
    const float* tok  = (const float*)d_in[0];
    const int*   bidx = (const int*)d_in[1];
    const int*   e1s  = (const int*)d_in[2];
    const int*   e1e  = (const int*)d_in[3];
    const int*   e2s  = (const int*)d_in[4];
    const int*   e2e  = (const int*)d_in[5];
    const int*   ridx = (const int*)d_in[6];
    const float* rtab = (const float*)d_in[7];
    float*       out  = (float*)d_out;

    const int P     = in_sizes[1];   // 8192
    const int njobs = 2 * P;         // 16384

    int* sorted = (int*)d_ws;        // njobs ints

    sort_jobs<<<1, 1024, 0, stream>>>(bidx, e1s, e2s, sorted, njobs);

    const int nblocks = njobs / GROUP;          // 4096 groups, full-width
    gather_lds<<<nblocks, 256, 0, stream>>>(
        tok, sorted, bidx, e1s, e1e, e2s, e2e, ridx, rtab, out);
}